// Round 1
// baseline (22111.121 us; speedup 1.0000x reference)
//
#include <hip/hip_runtime.h>
#include <hip/hip_bf16.h>
#include <math.h>

// Problem constants
constexpr int Bc = 4, Sc = 1024, Dc = 1024, Hc = 16, Lc = 4, Fc = 4096, Vc = 32000;
constexpr int DKc = 64;
constexpr int Mc = Bc * Sc;          // 4096 tokens
constexpr float EPSc = 1e-5f;

// ---------------------------------------------------------------------------
// Embedding + positional encoding: h[m,d] = emb[x[m],d]*32 + PE(s,d)
// ---------------------------------------------------------------------------
__global__ __launch_bounds__(256) void embed_k(const int* __restrict__ x,
                                               const float* __restrict__ emb,
                                               float* __restrict__ h) {
    int m = blockIdx.x;            // token index
    int s = m & (Sc - 1);          // position within sequence
    int tid = threadIdx.x;
    int d0 = tid * 4;
    int tok = x[m];
    float4 e = *(const float4*)&emb[(size_t)tok * Dc + d0];
    // pair indices p0, p0+1 ;  div[p] = exp(-ln(10000) * p / 512)
    const float c = -9.210340371976184f / 512.0f;   // -ln(10000)/(D/2)
    float p0 = (float)(tid * 2);
    float fs = (float)s;
    float ang0 = fs * __expf(c * p0);
    float ang1 = fs * __expf(c * (p0 + 1.0f));
    float4 o;
    o.x = e.x * 32.0f + sinf(ang0);
    o.y = e.y * 32.0f + cosf(ang0);
    o.z = e.z * 32.0f + sinf(ang1);
    o.w = e.w * 32.0f + cosf(ang1);
    *(float4*)&h[(size_t)m * Dc + d0] = o;
}

// ---------------------------------------------------------------------------
// Tiled fp32 GEMM: C[M,N] = A[M,K] @ B[K,N]  (+ epilogues)
// MODE 0: plain   MODE 1: +bias   MODE 2: +bias, exact GELU
// MODE 3: QKV scatter -> out[b, head, s, dk]  (no bias)
// BM=BN=64, BK=16, 256 threads, 4x4 micro-tile per thread
// ---------------------------------------------------------------------------
__device__ __forceinline__ float gelu_exact(float v) {
    return 0.5f * v * (1.0f + erff(v * 0.70710678118654752f));
}

template<int MODE>
__global__ __launch_bounds__(256) void gemm_k(const float* __restrict__ A,
                                              const float* __restrict__ Bm,
                                              const float* __restrict__ bias,
                                              float* __restrict__ C,
                                              int Kd, int Nd) {
    __shared__ float As[16][64];   // [k][m] (transposed)
    __shared__ float Bs[16][64];   // [k][n]
    int tid = threadIdx.x;
    int bm = blockIdx.y * 64;
    int bn = blockIdx.x * 64;
    int tx = tid & 15;             // col group
    int ty = tid >> 4;             // row group
    float acc[4][4] = {};

    int arow = tid >> 2;           // 0..63
    int akq  = tid & 3;            // k-quad
    int bkrow = tid >> 4;          // 0..15
    int bn4   = tid & 15;          // col-quad

    const float* Aptr = A + (size_t)(bm + arow) * Kd + akq * 4;
    const float* Bptr = Bm + (size_t)bkrow * Nd + bn + bn4 * 4;

    for (int k0 = 0; k0 < Kd; k0 += 16) {
        float4 av = *(const float4*)(Aptr + k0);
        float4 bv = *(const float4*)(Bptr + (size_t)k0 * Nd);
        As[akq * 4 + 0][arow] = av.x;
        As[akq * 4 + 1][arow] = av.y;
        As[akq * 4 + 2][arow] = av.z;
        As[akq * 4 + 3][arow] = av.w;
        *(float4*)&Bs[bkrow][bn4 * 4] = bv;
        __syncthreads();
#pragma unroll
        for (int kk = 0; kk < 16; kk++) {
            float4 a4 = *(const float4*)&As[kk][ty * 4];
            float4 b4 = *(const float4*)&Bs[kk][tx * 4];
            acc[0][0] += a4.x * b4.x; acc[0][1] += a4.x * b4.y;
            acc[0][2] += a4.x * b4.z; acc[0][3] += a4.x * b4.w;
            acc[1][0] += a4.y * b4.x; acc[1][1] += a4.y * b4.y;
            acc[1][2] += a4.y * b4.z; acc[1][3] += a4.y * b4.w;
            acc[2][0] += a4.z * b4.x; acc[2][1] += a4.z * b4.y;
            acc[2][2] += a4.z * b4.z; acc[2][3] += a4.z * b4.w;
            acc[3][0] += a4.w * b4.x; acc[3][1] += a4.w * b4.y;
            acc[3][2] += a4.w * b4.z; acc[3][3] += a4.w * b4.w;
        }
        __syncthreads();
    }

#pragma unroll
    for (int i = 0; i < 4; i++) {
        int gm = bm + ty * 4 + i;
#pragma unroll
        for (int j = 0; j < 4; j++) {
            int gn = bn + tx * 4 + j;
            float v = acc[i][j];
            if (MODE == 1 || MODE == 2) v += bias[gn];
            if (MODE == 2) v = gelu_exact(v);
            if (MODE == 3) {
                int b = gm >> 10, s = gm & 1023;
                int hh = gn >> 6, dk = gn & 63;
                C[(((size_t)(b * Hc + hh) * Sc) + s) * DKc + dk] = v;
            } else {
                C[(size_t)gm * Nd + gn] = v;
            }
        }
    }
}

// ---------------------------------------------------------------------------
// Attention: one block per (query row, batch*head). Q/K/V in [B,H,S,DK].
// Writes ctx in [B,S,D] layout (column = head*64 + dk).
// ---------------------------------------------------------------------------
__global__ __launch_bounds__(256) void attn_k(const float* __restrict__ Q,
                                              const float* __restrict__ K,
                                              const float* __restrict__ V,
                                              const int* __restrict__ x,
                                              float* __restrict__ ctx) {
    int qi = blockIdx.x;
    int bh = blockIdx.y;
    int b = bh >> 4;       // /H
    int hh = bh & 15;
    int tid = threadIdx.x;
    int lane = tid & 63, wid = tid >> 6;

    __shared__ float qs[64];
    __shared__ float sc[1024];
    __shared__ float red[8];
    __shared__ float part[4][64];

    const float* Kb = K + (size_t)bh * Sc * DKc;
    const float* Vb = V + (size_t)bh * Sc * DKc;

    if (tid < 64) qs[tid] = Q[((size_t)bh * Sc + qi) * DKc + tid];
    __syncthreads();

    // scores
    for (int j = tid; j < Sc; j += 256) {
        float dv = -INFINITY;
        if (j <= qi && x[b * Sc + j] != 0) {
            const float* kr = &Kb[(size_t)j * DKc];
            float s = 0.0f;
#pragma unroll
            for (int d = 0; d < 64; d++) s += qs[d] * kr[d];
            dv = s * 0.125f;
        }
        sc[j] = dv;
    }
    __syncthreads();

    // max reduce
    float mx = -INFINITY;
    for (int j = tid; j < Sc; j += 256) mx = fmaxf(mx, sc[j]);
    for (int off = 32; off; off >>= 1) mx = fmaxf(mx, __shfl_down(mx, off));
    if (lane == 0) red[wid] = mx;
    __syncthreads();
    if (tid == 0) red[0] = fmaxf(fmaxf(red[0], red[1]), fmaxf(red[2], red[3]));
    __syncthreads();
    mx = red[0];
    __syncthreads();

    // exp + sum
    float sum = 0.0f;
    for (int j = tid; j < Sc; j += 256) {
        float p = expf(sc[j] - mx);
        sc[j] = p;
        sum += p;
    }
    for (int off = 32; off; off >>= 1) sum += __shfl_down(sum, off);
    __syncthreads();
    if (lane == 0) red[wid] = sum;
    __syncthreads();
    if (tid == 0) red[0] = red[0] + red[1] + red[2] + red[3];
    __syncthreads();
    float inv = 1.0f / red[0];

    // ctx = P @ V ; thread (chunk, d) accumulates over 256 keys
    int d = tid & 63;
    int chunk = tid >> 6;
    float acc = 0.0f;
    int j0 = chunk * 256;
    int j1 = min(j0 + 256, qi + 1);
    for (int j = j0; j < j1; j++) acc += sc[j] * Vb[(size_t)j * DKc + d];
    part[chunk][d] = acc;
    __syncthreads();
    if (tid < 64) {
        float r = (part[0][tid] + part[1][tid] + part[2][tid] + part[3][tid]) * inv;
        ctx[((size_t)b * Sc + qi) * Dc + hh * 64 + tid] = r;
    }
}

// ---------------------------------------------------------------------------
// Residual add + LayerNorm over D=1024. One block per row (in-place on h ok).
// ---------------------------------------------------------------------------
__global__ __launch_bounds__(256) void lnadd_k(const float* x, const float* r,
                                               const float* __restrict__ g,
                                               const float* __restrict__ bb,
                                               float* out) {
    int row = blockIdx.x, tid = threadIdx.x;
    int lane = tid & 63, wid = tid >> 6;
    __shared__ float red[8];
    size_t base = (size_t)row * Dc + tid * 4;
    float4 xv = *(const float4*)(x + base);
    float4 rv = *(const float4*)(r + base);
    float v0 = xv.x + rv.x, v1 = xv.y + rv.y, v2 = xv.z + rv.z, v3 = xv.w + rv.w;
    float sum = v0 + v1 + v2 + v3;
    float sq = v0 * v0 + v1 * v1 + v2 * v2 + v3 * v3;
    for (int off = 32; off; off >>= 1) {
        sum += __shfl_down(sum, off);
        sq  += __shfl_down(sq, off);
    }
    if (lane == 0) { red[wid] = sum; red[4 + wid] = sq; }
    __syncthreads();
    if (tid == 0) {
        red[0] = red[0] + red[1] + red[2] + red[3];
        red[4] = red[4] + red[5] + red[6] + red[7];
    }
    __syncthreads();
    float mu = red[0] * (1.0f / Dc);
    float var = red[4] * (1.0f / Dc) - mu * mu;
    float rs = rsqrtf(var + EPSc);
    int d = tid * 4;
    float4 gv = *(const float4*)(g + d);
    float4 bv = *(const float4*)(bb + d);
    float4 o;
    o.x = (v0 - mu) * rs * gv.x + bv.x;
    o.y = (v1 - mu) * rs * gv.y + bv.y;
    o.z = (v2 - mu) * rs * gv.z + bv.z;
    o.w = (v3 - mu) * rs * gv.w + bv.w;
    *(float4*)(out + base) = o;
}

// ---------------------------------------------------------------------------
extern "C" void kernel_launch(void* const* d_in, const int* in_sizes, int n_in,
                              void* d_out, int out_size, void* d_ws, size_t ws_size,
                              hipStream_t stream) {
    const int*   x     = (const int*)d_in[0];
    const float* emb   = (const float*)d_in[1];
    const float* Wq    = (const float*)d_in[2];
    const float* Wk    = (const float*)d_in[3];
    const float* Wv    = (const float*)d_in[4];
    const float* Wo    = (const float*)d_in[5];
    const float* bo    = (const float*)d_in[6];
    const float* ln1g  = (const float*)d_in[7];
    const float* ln1b  = (const float*)d_in[8];
    const float* ln2g  = (const float*)d_in[9];
    const float* ln2b  = (const float*)d_in[10];
    const float* W1    = (const float*)d_in[11];
    const float* b1    = (const float*)d_in[12];
    const float* W2    = (const float*)d_in[13];
    const float* b2    = (const float*)d_in[14];
    const float* Wout  = (const float*)d_in[15];
    const float* bout  = (const float*)d_in[16];
    float* out = (float*)d_out;
    float* ws = (float*)d_ws;

    const size_t MD = (size_t)Mc * Dc;   // 4M floats
    float* h    = ws;
    float* q    = ws + 1 * MD;
    float* k    = ws + 2 * MD;
    float* v    = ws + 3 * MD;
    float* ctx  = ws + 4 * MD;
    float* tmp  = ws + 5 * MD;           // attn_out / ff2
    float* ff1  = q;                     // reuses q..ctx span (16M floats = M*F)

    embed_k<<<Mc, 256, 0, stream>>>(x, emb, h);

    dim3 gridDD(Dc / 64, Mc / 64);       // N=1024 tiles
    dim3 gridDF(Fc / 64, Mc / 64);       // N=4096 tiles
    dim3 gridOut(Vc / 64, Mc / 64);      // N=32000 tiles

    for (int l = 0; l < Lc; l++) {
        const float* wq = Wq + (size_t)l * Dc * Dc;
        const float* wk = Wk + (size_t)l * Dc * Dc;
        const float* wv = Wv + (size_t)l * Dc * Dc;
        const float* wo = Wo + (size_t)l * Dc * Dc;
        const float* w1 = W1 + (size_t)l * Dc * Fc;
        const float* w2 = W2 + (size_t)l * Fc * Dc;

        gemm_k<3><<<gridDD, 256, 0, stream>>>(h, wq, nullptr, q, Dc, Dc);
        gemm_k<3><<<gridDD, 256, 0, stream>>>(h, wk, nullptr, k, Dc, Dc);
        gemm_k<3><<<gridDD, 256, 0, stream>>>(h, wv, nullptr, v, Dc, Dc);

        attn_k<<<dim3(Sc, Bc * Hc), 256, 0, stream>>>(q, k, v, x, ctx);

        gemm_k<1><<<gridDD, 256, 0, stream>>>(ctx, wo, bo + l * Dc, tmp, Dc, Dc);
        lnadd_k<<<Mc, 256, 0, stream>>>(h, tmp, ln1g + l * Dc, ln1b + l * Dc, h);

        gemm_k<2><<<gridDF, 256, 0, stream>>>(h, w1, b1 + l * Fc, ff1, Dc, Fc);
        gemm_k<1><<<gridDD, 256, 0, stream>>>(ff1, w2, b2 + l * Dc, tmp, Fc, Dc);
        lnadd_k<<<Mc, 256, 0, stream>>>(h, tmp, ln2g + l * Dc, ln2b + l * Dc, h);
    }

    gemm_k<1><<<gridOut, 256, 0, stream>>>(h, Wout, bout, out, Dc, Vc);
}